// Round 1
// baseline (692.126 us; speedup 1.0000x reference)
//
#include <hip/hip_runtime.h>

// Problem constants (match reference.py)
#define B_ROWS  1048576
#define DIM     64
#define HOT     1000000
#define HASH    500000
#define MED     750000

// ---------------------------------------------------------------------------
// Kernel 0: detect whether the bool mask arrays were uploaded as 1-byte bools
// or as int32 (0/1). If int32, every byte at offset %4 != 0 is zero. If
// 1-byte bools, ~75% of the nonzero entries land at %4 != 0 within the first
// 64 KiB, so the probability of a false negative is ~0.
// Writes flag (0 = int32 layout, 1 = byte layout) into d_ws.
// Runs every launch (graph-capture safe, same work every call).
// ---------------------------------------------------------------------------
__global__ void detect_mask_layout(const unsigned char* __restrict__ m,
                                   int nbytes, int* __restrict__ flag) {
    __shared__ int any;
    if (threadIdx.x == 0) any = 0;
    __syncthreads();
    int local = 0;
    for (int i = threadIdx.x; i < nbytes; i += blockDim.x) {
        if ((i & 3) != 0 && m[i] != 0) local = 1;
    }
    if (local) atomicOr(&any, 1);
    __syncthreads();
    if (threadIdx.x == 0) *flag = any;
}

// ---------------------------------------------------------------------------
// Main kernel: 16 lanes per output row, one float4 (16 B) per lane => each
// row's 256 B is one fully-coalesced access group. 4 rows per wave.
// Branches are uniform across each 16-lane group.
// ---------------------------------------------------------------------------
__global__ void embed_bag_kernel(const int*  __restrict__ dic,
                                 const void* __restrict__ mask1_p,
                                 const void* __restrict__ mask2_p,
                                 const float* __restrict__ wh,
                                 const float* __restrict__ whash,
                                 const float* __restrict__ wmed,
                                 float* __restrict__ out,
                                 const int* __restrict__ flagp) {
    const int lane16 = threadIdx.x & 15;
    const long long gtid = (long long)blockIdx.x * blockDim.x + threadIdx.x;
    const int group0   = (int)(gtid >> 4);                       // row handled first
    const int ngroups  = (int)(((long long)gridDim.x * blockDim.x) >> 4);
    const bool bytemask = (*flagp != 0);                          // uniform

    const unsigned char* m1b = (const unsigned char*)mask1_p;
    const unsigned char* m2b = (const unsigned char*)mask2_p;
    const int* m1i = (const int*)mask1_p;
    const int* m2i = (const int*)mask2_p;

    for (int row = group0; row < B_ROWS; row += ngroups) {
        const int idx = dic[row];
        bool mask, maskm;
        if (bytemask) {
            mask  = m1b[row] != 0;
            maskm = m2b[row] != 0;
        } else {
            mask  = m1i[row] != 0;
            maskm = m2i[row] != 0;
        }

        float4 v;
        if (mask) {
            const float4* src =
                (const float4*)(wh + (long long)(idx % HOT) * DIM);
            v = src[lane16];
        } else {
            const float4* s1 =
                (const float4*)(whash + (long long)(idx % HASH) * DIM);
            v = s1[lane16];
            if (maskm) {
                const float4* s2 =
                    (const float4*)(wmed + (long long)(idx % MED) * DIM);
                const float4 u = s2[lane16];
                v.x += u.x; v.y += u.y; v.z += u.z; v.w += u.w;
            }
        }
        ((float4*)(out + (long long)row * DIM))[lane16] = v;
    }
}

extern "C" void kernel_launch(void* const* d_in, const int* in_sizes, int n_in,
                              void* d_out, int out_size, void* d_ws, size_t ws_size,
                              hipStream_t stream) {
    // setup_inputs() order:
    // 0: dic (int32, B)        1: dic_mask (bool, B)   2: dic_mask_median (bool, B)
    // 3: offsets (int32, B)    4: weight_h (f32, HOT*D)
    // 5: weight_hash (f32, HASH*D)                    6: weight_median (f32, MED*D)
    const int*  dic   = (const int*)d_in[0];
    const void* m1    = d_in[1];
    const void* m2    = d_in[2];
    const float* wh    = (const float*)d_in[4];
    const float* whash = (const float*)d_in[5];
    const float* wmed  = (const float*)d_in[6];
    float* out = (float*)d_out;
    int* flag = (int*)d_ws;

    // Detect mask element size (scan 64 KiB of dic_mask; buffer is >= 1 MiB
    // in either layout, so this never reads out of bounds).
    detect_mask_layout<<<1, 256, 0, stream>>>((const unsigned char*)m1, 65536, flag);

    const int block = 256;
    const int grid  = 2048;   // 524288 threads = 32768 rows per sweep, grid-stride
    embed_bag_kernel<<<grid, block, 0, stream>>>(dic, m1, m2, wh, whash, wmed,
                                                 out, flag);
}